// Round 6
// baseline (6899.565 us; speedup 1.0000x reference)
//
#include <hip/hip_runtime.h>

typedef unsigned short u16;
typedef short s16x8 __attribute__((ext_vector_type(8)));

#define S_TXTC 512
#define S_TOTC 2560
#define DM 3072
#define NH 24
#define HDM 128

__device__ __forceinline__ float b2f(u16 u){ unsigned int i = ((unsigned int)u)<<16; float f; __builtin_memcpy(&f,&i,4); return f; }
__device__ __forceinline__ u16 f2b(float f){ unsigned int i; __builtin_memcpy(&i,&f,4); unsigned int r = i + 0x7FFFu + ((i>>16)&1u); return (u16)(r>>16); }

// ---------------- diagnostic fill ----------------
__global__ __launch_bounds__(256) void fill7(float* __restrict__ p, int n){
  int i = blockIdx.x*256 + threadIdx.x;
  if (i < n) p[i] = 7.0f;
}

// ---------------- naive-but-tiled fp32 GEMM: C[M][3072] = A_f32 @ W_f32 + bias ----------------
// W is [3072][3072] row-major (k-major, used directly). 64x64 tile, 256 thr, 4x4/thread.
// OUT32=0 -> bf16 u16 output; OUT32=1 -> fp32 output.
template<int OUT32>
__global__ __launch_bounds__(256) void gemm_naive(const float* __restrict__ A, const float* __restrict__ W,
                                                  const float* __restrict__ bias, void* __restrict__ Cv){
  __shared__ float As[64][33];
  __shared__ float Ws[32][65];
  int rb = blockIdx.x*64, cb = blockIdx.y*64;
  int tid = threadIdx.x;
  int tm = tid>>4, tn = tid&15;
  float acc[4][4] = {};
  for (int ks=0; ks<DM; ks+=32){
    {
      int ar = tid>>2, ac = (tid&3)*8;
      const float* p = A + (size_t)(rb+ar)*DM + ks + ac;
      #pragma unroll
      for (int e=0;e<8;e++) As[ar][ac+e] = p[e];
    }
    {
      int wr_ = tid>>3, wc_ = (tid&7)*8;
      const float* p = W + (size_t)(ks+wr_)*DM + cb + wc_;
      #pragma unroll
      for (int e=0;e<8;e++) Ws[wr_][wc_+e] = p[e];
    }
    __syncthreads();
    #pragma unroll 8
    for (int kk=0; kk<32; kk++){
      float a0=As[tm*4+0][kk], a1=As[tm*4+1][kk], a2=As[tm*4+2][kk], a3=As[tm*4+3][kk];
      float w0=Ws[kk][tn*4+0], w1=Ws[kk][tn*4+1], w2=Ws[kk][tn*4+2], w3=Ws[kk][tn*4+3];
      acc[0][0]+=a0*w0; acc[0][1]+=a0*w1; acc[0][2]+=a0*w2; acc[0][3]+=a0*w3;
      acc[1][0]+=a1*w0; acc[1][1]+=a1*w1; acc[1][2]+=a1*w2; acc[1][3]+=a1*w3;
      acc[2][0]+=a2*w0; acc[2][1]+=a2*w1; acc[2][2]+=a2*w2; acc[2][3]+=a2*w3;
      acc[3][0]+=a3*w0; acc[3][1]+=a3*w1; acc[3][2]+=a3*w2; acc[3][3]+=a3*w3;
    }
    __syncthreads();
  }
  #pragma unroll
  for (int i=0;i<4;i++){
    int row = rb + tm*4 + i;
    #pragma unroll
    for (int j=0;j<4;j++){
      int col = cb + tn*4 + j;
      float oo = acc[i][j] + (bias ? bias[col] : 0.f);
      if (OUT32) ((float*)Cv)[(size_t)row*DM + col] = oo;
      else       ((u16*)Cv)[(size_t)row*DM + col] = f2b(oo);
    }
  }
}

// ---------------- epilogue q,k: per-head RMSNorm + RoPE, gather to [H][S_TOT][HD] (bf16) ----------------
__global__ __launch_bounds__(256) void epi_qk(
    const u16* __restrict__ qri, const u16* __restrict__ qrt,
    const u16* __restrict__ kri, const u16* __restrict__ krt,
    const float* __restrict__ nqw, const float* __restrict__ nkw,
    const float* __restrict__ naq, const float* __restrict__ nak,
    const float* __restrict__ fcos, const float* __restrict__ fsin,
    u16* __restrict__ qh, u16* __restrict__ kh){
  int wid = blockIdx.x*4 + (threadIdx.x>>6);
  int lane = threadIdx.x&63;
  int which = wid / (NH*S_TOTC);
  int rem = wid % (NH*S_TOTC);
  int h = rem / S_TOTC, tok = rem % S_TOTC;
  const u16* src; const float* nw;
  if (which==0){ src = (tok<S_TXTC)? qrt + (size_t)tok*DM : qri + (size_t)(tok-S_TXTC)*DM; nw = (tok<S_TXTC)? naq : nqw; }
  else        { src = (tok<S_TXTC)? krt + (size_t)tok*DM : kri + (size_t)(tok-S_TXTC)*DM; nw = (tok<S_TXTC)? nak : nkw; }
  int d = lane*2;
  unsigned int u = *(const unsigned int*)(src + h*HDM + d);
  float x0 = b2f((u16)(u&0xffffu)), x1 = b2f((u16)(u>>16));
  float ss = x0*x0 + x1*x1;
  #pragma unroll
  for (int m=1;m<64;m<<=1) ss += __shfl_xor(ss, m);
  float rr = rsqrtf(ss*(1.f/128.f) + 1e-6f);
  float y0 = x0*rr*nw[d];
  float y1 = x1*rr*nw[d+1];
  float2 cc = *(const float2*)(fcos + (size_t)tok*HDM + d);
  float2 sn = *(const float2*)(fsin + (size_t)tok*HDM + d);
  float o0 = y0*cc.x - y1*sn.x;
  float o1 = y1*cc.y + y0*sn.y;
  u16* dst = (which? kh : qh) + ((size_t)h*S_TOTC + tok)*HDM + d;
  *(unsigned int*)dst = (unsigned int)f2b(o0) | ((unsigned int)f2b(o1)<<16);
}

// ---------------- epilogue v: gather to vh[H][S_TOT][HD] (bf16, head-major) ----------------
__global__ __launch_bounds__(256) void epi_vg(const u16* __restrict__ vri, const u16* __restrict__ vrt,
                                              u16* __restrict__ vh){
  int wid = blockIdx.x*4 + (threadIdx.x>>6);
  int lane = threadIdx.x&63;
  int h = wid / S_TOTC, tok = wid % S_TOTC;
  const u16* src = (tok<S_TXTC)? vrt + (size_t)tok*DM : vri + (size_t)(tok-S_TXTC)*DM;
  int d = lane*2;
  *(unsigned int*)(vh + ((size_t)h*S_TOTC + tok)*HDM + d) = *(const unsigned int*)(src + h*HDM + d);
}

// ---------------- adapter projections: f32 (4x1024)@(1024x3072) -> bf16 [H][4][HD] ----------------
__global__ __launch_bounds__(256) void adapterk(const float* __restrict__ ad, const float* __restrict__ Wk,
        const float* __restrict__ Wv, u16* __restrict__ vdk, u16* __restrict__ vdv){
  int wid = blockIdx.x*4 + (threadIdx.x>>6);
  int lane = threadIdx.x&63;
  int tensor = wid / (4*DM);
  int rem = wid % (4*DM);
  int tok = rem / DM, col = rem % DM;
  const float* Wp = tensor? Wv : Wk;
  float s = 0.f;
  #pragma unroll
  for (int i=0;i<16;i++){
    int k = lane + 64*i;
    s += ad[tok*1024 + k] * Wp[(size_t)k*DM + col];
  }
  #pragma unroll
  for (int m=1;m<64;m<<=1) s += __shfl_xor(s, m);
  if (lane==0){
    int hh = col>>7, d = col&127;
    (tensor? vdv : vdk)[(hh*4+tok)*HDM + d] = f2b(s);
  }
}

// ---------------- NAIVE flash attention (VALU only) ----------------
__global__ __launch_bounds__(256) void attnk_naive(const u16* __restrict__ qh, const u16* __restrict__ kh,
    const u16* __restrict__ vh, const u16* __restrict__ vdk, const u16* __restrict__ vdv,
    const float* __restrict__ bscale, float* __restrict__ hs){
  __shared__ __align__(16) u16 kt[32*128];
  __shared__ __align__(16) u16 vt2[32*128];
  int h = blockIdx.y, qb = blockIdx.x*64;
  int tid = threadIdx.x;
  int q = tid>>2, sl = tid&3;
  int tok = qb + q;
  float qv[32];
  const u16* qrow = qh + ((size_t)h*S_TOTC + tok)*HDM + sl*32;
  #pragma unroll
  for (int j=0;j<32;j+=8){
    s16x8 v8 = *(const s16x8*)(qrow + j);
    #pragma unroll
    for (int e=0;e<8;e++) qv[j+e] = b2f((u16)v8[e]);
  }
  float m_ = -3e38f, l_ = 0.f;
  float acc[32];
  #pragma unroll
  for (int j=0;j<32;j++) acc[j] = 0.f;
  const float scl = 0.08838834764831845f;
  for (int kb=0; kb<S_TOTC; kb+=32){
    for (int e=tid; e<512; e+=256){
      int key = e>>4, c8 = (e&15)*8;
      *(s16x8*)&kt[key*128 + c8]  = *(const s16x8*)(kh + ((size_t)h*S_TOTC + kb + key)*HDM + c8);
      *(s16x8*)&vt2[key*128 + c8] = *(const s16x8*)(vh + ((size_t)h*S_TOTC + kb + key)*HDM + c8);
    }
    __syncthreads();
    for (int key=0; key<32; key++){
      float part = 0.f;
      const u16* kr = &kt[key*128 + sl*32];
      #pragma unroll
      for (int j=0;j<32;j+=8){
        s16x8 v8 = *(const s16x8*)(kr + j);
        #pragma unroll
        for (int e=0;e<8;e++) part += qv[j+e]*b2f((u16)v8[e]);
      }
      part += __shfl_xor(part, 1);
      part += __shfl_xor(part, 2);
      float s = part * scl;
      float mn = fmaxf(m_, s);
      float c = __expf(m_ - mn), p = __expf(s - mn);
      m_ = mn; l_ = l_*c + p;
      const u16* vr = &vt2[key*128 + sl*32];
      #pragma unroll
      for (int j=0;j<32;j+=8){
        s16x8 v8 = *(const s16x8*)(vr + j);
        #pragma unroll
        for (int e=0;e<8;e++) acc[j+e] = acc[j+e]*c + p*b2f((u16)v8[e]);
      }
    }
    __syncthreads();
  }
  float m2 = -3e38f, l2 = 0.f;
  float a2[32];
  #pragma unroll
  for (int j=0;j<32;j++) a2[j] = 0.f;
  for (int key=0; key<4; key++){
    float part = 0.f;
    const u16* kr = vdk + (h*4+key)*HDM + sl*32;
    #pragma unroll
    for (int j=0;j<32;j+=8){
      s16x8 v8 = *(const s16x8*)(kr + j);
      #pragma unroll
      for (int e=0;e<8;e++) part += qv[j+e]*b2f((u16)v8[e]);
    }
    part += __shfl_xor(part, 1);
    part += __shfl_xor(part, 2);
    float s = part * scl;
    float mn = fmaxf(m2, s);
    float c = __expf(m2 - mn), p = __expf(s - mn);
    m2 = mn; l2 = l2*c + p;
    const u16* vr = vdv + (h*4+key)*HDM + sl*32;
    #pragma unroll
    for (int j=0;j<32;j+=8){
      s16x8 v8 = *(const s16x8*)(vr + j);
      #pragma unroll
      for (int e=0;e<8;e++) a2[j+e] = a2[j+e]*c + p*b2f((u16)v8[e]);
    }
  }
  float sb = bscale[0];
  float* orow = hs + (size_t)tok*DM + h*HDM + sl*32;
  #pragma unroll
  for (int j=0;j<32;j++) orow[j] = acc[j]/l_ + sb*(a2[j]/l2);
}

extern "C" void kernel_launch(void* const* d_in, const int* in_sizes, int n_in,
                              void* d_out, int out_size, void* d_ws, size_t ws_size,
                              hipStream_t stream){
  // --- contract guard: verify dict-order input sizes; mismatch -> 7.0 signature ---
  static const int expect[28] = {
    6291456, 1572864, 4096, 327680, 327680,
    9437184, 3072, 9437184, 3072, 9437184, 3072, 128, 128,
    9437184, 3072, 9437184, 3072, 9437184, 3072, 128, 128,
    9437184, 3072, 9437184, 3072, 3145728, 3145728, 1 };
  bool ok = (n_in == 28);
  if (ok) for (int i=0;i<28;i++) if (in_sizes[i] != expect[i]) { ok = false; break; }
  if (!ok){
    fill7<<<(out_size+255)/256,256,0,stream>>>((float*)d_out, out_size);
    return;
  }

  const float* hidden = (const float*)d_in[0];
  const float* enc    = (const float*)d_in[1];
  const float* adapt  = (const float*)d_in[2];
  const float* fcos   = (const float*)d_in[3];
  const float* fsin   = (const float*)d_in[4];
  const float* Wq  = (const float*)d_in[5];  const float* bq  = (const float*)d_in[6];
  const float* Wk  = (const float*)d_in[7];  const float* bk  = (const float*)d_in[8];
  const float* Wv  = (const float*)d_in[9];  const float* bv  = (const float*)d_in[10];
  const float* nqw = (const float*)d_in[11]; const float* nkw = (const float*)d_in[12];
  const float* Wqa = (const float*)d_in[13]; const float* bqa = (const float*)d_in[14];
  const float* Wka = (const float*)d_in[15]; const float* bka = (const float*)d_in[16];
  const float* Wva = (const float*)d_in[17]; const float* bva = (const float*)d_in[18];
  const float* naq = (const float*)d_in[19]; const float* nak = (const float*)d_in[20];
  const float* Wo  = (const float*)d_in[21]; const float* bo  = (const float*)d_in[22];
  const float* Woa = (const float*)d_in[23]; const float* boa = (const float*)d_in[24];
  const float* Wkad = (const float*)d_in[25]; const float* Wvad = (const float*)d_in[26];
  const float* bsc  = (const float*)d_in[27];
  float* out = (float*)d_out;   // fp32 output per doc: reference output dtype is float32

  // ws layout (bytes), peak ~94 MB
  char* ws = (char*)d_ws;
  u16* qri  = (u16*)(ws);                 // 12,582,912 each (2048x3072 bf16)
  u16* kri  = (u16*)(ws + 12582912);
  u16* vri  = (u16*)(ws + 25165824);
  u16* qrt  = (u16*)(ws + 37748736);      // 3,145,728 each (512x3072 bf16)
  u16* krt  = (u16*)(ws + 40894464);
  u16* vrt  = (u16*)(ws + 44040192);
  u16* qh   = (u16*)(ws + 47185920);      // 15,728,640 each (24x2560x128 bf16)
  u16* kh   = (u16*)(ws + 62914560);
  u16* vh   = (u16*)(ws + 78643200);      // ends 94,371,840
  u16*   vdk = (u16*)(ws + 37748736);     // qrt slot (dead after epi_qk)
  u16*   vdv = (u16*)(ws + 37773312);
  float* hsb = (float*)(ws);              // fp32 2560x3072 = 31,457,280 B (qri/kri/vri region, dead at attnk)

  // QKV projections (fp32 VALU GEMM, W used directly) -> bf16 intermediates
  gemm_naive<0><<<dim3(32,48),256,0,stream>>>(hidden, Wq, bq, qri);
  gemm_naive<0><<<dim3(32,48),256,0,stream>>>(hidden, Wk, bk, kri);
  gemm_naive<0><<<dim3(32,48),256,0,stream>>>(hidden, Wv, bv, vri);
  gemm_naive<0><<<dim3(8,48),256,0,stream>>>(enc, Wqa, bqa, qrt);
  gemm_naive<0><<<dim3(8,48),256,0,stream>>>(enc, Wka, bka, krt);
  gemm_naive<0><<<dim3(8,48),256,0,stream>>>(enc, Wva, bva, vrt);
  // epilogues + adapter
  epi_qk<<<30720,256,0,stream>>>(qri,qrt,kri,krt,nqw,nkw,naq,nak,fcos,fsin,qh,kh);
  epi_vg<<<15360,256,0,stream>>>(vri,vrt,vh);
  adapterk<<<6144,256,0,stream>>>(adapt, Wkad, Wvad, vdk, vdv);
  // attention (naive VALU) -> fp32 hsb
  attnk_naive<<<dim3(40,24),256,0,stream>>>(qh,kh,vh,vdk,vdv,bsc,hsb);
  // output projections -> fp32 d_out: img rows first (return order: img_out, enc_out)
  gemm_naive<1><<<dim3(8,48),256,0,stream>>>(hsb, Woa, boa, out + (size_t)2048*3072);
  gemm_naive<1><<<dim3(32,48),256,0,stream>>>(hsb + (size_t)512*3072, Wo, bo, out);
}

// Round 7
// 1370.067 us; speedup vs baseline: 5.0359x; 5.0359x over previous
//
#include <hip/hip_runtime.h>

typedef unsigned short u16;
typedef short s16x8 __attribute__((ext_vector_type(8)));
typedef float f32x4 __attribute__((ext_vector_type(4)));

#define S_TXTC 512
#define S_TOTC 2560
#define DM 3072
#define NH 24
#define HDM 128

__device__ __forceinline__ float b2f(u16 u){ unsigned int i = ((unsigned int)u)<<16; float f; __builtin_memcpy(&f,&i,4); return f; }
__device__ __forceinline__ u16 f2b(float f){ unsigned int i; __builtin_memcpy(&i,&f,4); unsigned int r = i + 0x7FFFu + ((i>>16)&1u); return (u16)(r>>16); }
__device__ __forceinline__ s16x8 pk8(float4 a, float4 b){
  s16x8 r;
  r[0]=(short)f2b(a.x); r[1]=(short)f2b(a.y); r[2]=(short)f2b(a.z); r[3]=(short)f2b(a.w);
  r[4]=(short)f2b(b.x); r[5]=(short)f2b(b.y); r[6]=(short)f2b(b.z); r[7]=(short)f2b(b.w);
  return r;
}

__global__ __launch_bounds__(256) void fill7(float* __restrict__ p, int n){
  int i = blockIdx.x*256 + threadIdx.x;
  if (i < n) p[i] = 7.0f;
}

// ---------------- transpose+cast 3072x3072: Wt_bf16[n][k] = W_f32[k][n] ----------------
__global__ __launch_bounds__(256) void ktrans(const float* __restrict__ W, u16* __restrict__ Wt){
  __shared__ __align__(16) u16 t[64*72];
  int nt = blockIdx.x*64, kt_ = blockIdx.y*64;
  int tid = threadIdx.x;
  #pragma unroll
  for (int i=0;i<2;i++){
    int q = tid + 256*i;
    int r = q>>3, c8 = (q&7)*8;
    float4 f0 = *(const float4*)(W + (size_t)(kt_+r)*DM + nt + c8);
    float4 f1 = *(const float4*)(W + (size_t)(kt_+r)*DM + nt + c8 + 4);
    *(s16x8*)&t[r*72 + c8] = pk8(f0,f1);
  }
  __syncthreads();
  #pragma unroll
  for (int i=0;i<2;i++){
    int q = tid + 256*i;
    int n = q>>3, k8 = (q&7)*8;
    s16x8 v;
    #pragma unroll
    for (int j=0;j<8;j++) v[j] = (short)t[(k8+j)*72 + n];
    *(s16x8*)(Wt + (size_t)(nt+n)*DM + kt_ + k8) = v;
  }
}

// ---------------- MFMA GEMM: C[m][n] = sum_k A_f32[m][k]*Bt_bf16[n][k] + bias[n] ----------------
// 128x128 tile, 4 waves (2x2), BK=32, reg-staged LDS (padded stride 40), 16x16x32 MFMA
// OUT32=0 -> bf16 out, OUT32=1 -> fp32 out
template<int OUT32>
__global__ __launch_bounds__(256) void gemm128(const float* __restrict__ A, const u16* __restrict__ Bt,
                                               const float* __restrict__ bias, void* __restrict__ Cv){
  __shared__ __align__(16) u16 la[128*40];
  __shared__ __align__(16) u16 lb[128*40];
  const int K = DM;
  int rb = blockIdx.x*128, cb = blockIdx.y*128;
  int tid = threadIdx.x, w = tid>>6, l = tid&63, g = l>>4, c16 = l&15;
  int wr = (w>>1)*64, wc = (w&1)*64;
  f32x4 acc[4][4] = {};
  int srow = tid>>2, skc = (tid&3)*8;
  const float* aP  = A  + (size_t)(rb + srow)*K + skc;
  const float* aP2 = A  + (size_t)(rb + 64 + srow)*K + skc;
  const u16* bP  = Bt + (size_t)(cb + srow)*K + skc;
  const u16* bP2 = Bt + (size_t)(cb + 64 + srow)*K + skc;
  for (int ks=0; ks<K; ks+=32){
    float4 a0 = *(const float4*)(aP  + ks), a0b = *(const float4*)(aP  + ks + 4);
    float4 a1 = *(const float4*)(aP2 + ks), a1b = *(const float4*)(aP2 + ks + 4);
    s16x8 b0 = *(const s16x8*)(bP  + ks);
    s16x8 b1 = *(const s16x8*)(bP2 + ks);
    *(s16x8*)&la[srow*40 + skc]      = pk8(a0,a0b);
    *(s16x8*)&la[(64+srow)*40 + skc] = pk8(a1,a1b);
    *(s16x8*)&lb[srow*40 + skc]      = b0;
    *(s16x8*)&lb[(64+srow)*40 + skc] = b1;
    __syncthreads();
    s16x8 af[4], bfr[4];
    #pragma unroll
    for (int m=0;m<4;m++) af[m]  = *(const s16x8*)&la[(wr + m*16 + c16)*40 + g*8];
    #pragma unroll
    for (int n=0;n<4;n++) bfr[n] = *(const s16x8*)&lb[(wc + n*16 + c16)*40 + g*8];
    #pragma unroll
    for (int m=0;m<4;m++)
      #pragma unroll
      for (int n=0;n<4;n++)
        acc[m][n] = __builtin_amdgcn_mfma_f32_16x16x32_bf16(af[m], bfr[n], acc[m][n], 0,0,0);
    __syncthreads();
  }
  #pragma unroll
  for (int n=0;n<4;n++){
    int col = cb + wc + n*16 + c16;
    float bv = bias ? bias[col] : 0.f;
    #pragma unroll
    for (int m=0;m<4;m++){
      int r0 = rb + wr + m*16 + g*4;
      #pragma unroll
      for (int r=0;r<4;r++){
        float oo = acc[m][n][r] + bv;
        if (OUT32) ((float*)Cv)[(size_t)(r0+r)*DM + col] = oo;
        else       ((u16*)Cv)[(size_t)(r0+r)*DM + col] = f2b(oo);
      }
    }
  }
}

// ---------------- epilogue q,k: per-head RMSNorm + RoPE, gather to [H][S_TOT][HD] (bf16) ----------------
__global__ __launch_bounds__(256) void epi_qk(
    const u16* __restrict__ qri, const u16* __restrict__ qrt,
    const u16* __restrict__ kri, const u16* __restrict__ krt,
    const float* __restrict__ nqw, const float* __restrict__ nkw,
    const float* __restrict__ naq, const float* __restrict__ nak,
    const float* __restrict__ fcos, const float* __restrict__ fsin,
    u16* __restrict__ qh, u16* __restrict__ kh){
  int wid = blockIdx.x*4 + (threadIdx.x>>6);
  int lane = threadIdx.x&63;
  int which = wid / (NH*S_TOTC);
  int rem = wid % (NH*S_TOTC);
  int h = rem / S_TOTC, tok = rem % S_TOTC;
  const u16* src; const float* nw;
  if (which==0){ src = (tok<S_TXTC)? qrt + (size_t)tok*DM : qri + (size_t)(tok-S_TXTC)*DM; nw = (tok<S_TXTC)? naq : nqw; }
  else        { src = (tok<S_TXTC)? krt + (size_t)tok*DM : kri + (size_t)(tok-S_TXTC)*DM; nw = (tok<S_TXTC)? nak : nkw; }
  int d = lane*2;
  unsigned int u = *(const unsigned int*)(src + h*HDM + d);
  float x0 = b2f((u16)(u&0xffffu)), x1 = b2f((u16)(u>>16));
  float ss = x0*x0 + x1*x1;
  #pragma unroll
  for (int m=1;m<64;m<<=1) ss += __shfl_xor(ss, m);
  float rr = rsqrtf(ss*(1.f/128.f) + 1e-6f);
  float y0 = x0*rr*nw[d];
  float y1 = x1*rr*nw[d+1];
  float2 cc = *(const float2*)(fcos + (size_t)tok*HDM + d);
  float2 sn = *(const float2*)(fsin + (size_t)tok*HDM + d);
  float o0 = y0*cc.x - y1*sn.x;
  float o1 = y1*cc.y + y0*sn.y;
  u16* dst = (which? kh : qh) + ((size_t)h*S_TOTC + tok)*HDM + d;
  *(unsigned int*)dst = (unsigned int)f2b(o0) | ((unsigned int)f2b(o1)<<16);
}

// ---------------- epilogue v: gather + transpose to v_t[H][HD][S_TOT] (bf16) ----------------
__global__ __launch_bounds__(256) void epi_v(const u16* __restrict__ vri, const u16* __restrict__ vrt,
                                             u16* __restrict__ vt){
  __shared__ __align__(16) u16 t[64*136];
  int h = blockIdx.x % NH, tb = blockIdx.x / NH;
  int tok0 = tb*64, tid = threadIdx.x;
  #pragma unroll
  for (int i=0;i<4;i++){
    int q = tid + 256*i;
    int tr = q>>4, c8 = (q&15)*8;
    int tok = tok0 + tr;
    const u16* src = (tok<S_TXTC)? vrt + (size_t)tok*DM : vri + (size_t)(tok-S_TXTC)*DM;
    *(s16x8*)&t[tr*136 + c8] = *(const s16x8*)(src + h*HDM + c8);
  }
  __syncthreads();
  #pragma unroll
  for (int i=0;i<4;i++){
    int q = tid + 256*i;
    int d = q>>3, j8 = (q&7)*8;
    s16x8 v;
    #pragma unroll
    for (int j=0;j<8;j++) v[j] = (short)t[(j8+j)*136 + d];
    *(s16x8*)(vt + ((size_t)h*HDM + d)*S_TOTC + tok0 + j8) = v;
  }
}

// ---------------- adapter projections: f32 (4x1024)@(1024x3072) -> bf16 [H][4][HD] ----------------
__global__ __launch_bounds__(256) void adapterk(const float* __restrict__ ad, const float* __restrict__ Wk,
        const float* __restrict__ Wv, u16* __restrict__ vdk, u16* __restrict__ vdv){
  int wid = blockIdx.x*4 + (threadIdx.x>>6);
  int lane = threadIdx.x&63;
  int tensor = wid / (4*DM);
  int rem = wid % (4*DM);
  int tok = rem / DM, col = rem % DM;
  const float* Wp = tensor? Wv : Wk;
  float s = 0.f;
  #pragma unroll
  for (int i=0;i<16;i++){
    int k = lane + 64*i;
    s += ad[tok*1024 + k] * Wp[(size_t)k*DM + col];
  }
  #pragma unroll
  for (int m=1;m<64;m<<=1) s += __shfl_xor(s, m);
  if (lane==0){
    int hh = col>>7, d = col&127;
    (tensor? vdv : vdk)[(hh*4+tok)*HDM + d] = f2b(s);
  }
}

// ---------------- fused MFMA flash attention (main joint + adapter cross), fp32 out ----------------
__global__ __launch_bounds__(256) void attnk(const u16* __restrict__ qh, const u16* __restrict__ kh,
    const u16* __restrict__ vt, const u16* __restrict__ vdk, const u16* __restrict__ vdv,
    const float* __restrict__ bscale, float* __restrict__ hs){
  __shared__ __align__(16) u16 kts[32*136];
  __shared__ __align__(16) u16 vts[128*40];
  __shared__ __align__(16) u16 pwb[64*40];
  __shared__ __align__(16) u16 kad[16*136];
  __shared__ __align__(16) u16 vad[128*40];
  int h = blockIdx.y, qb = blockIdx.x*64;
  int tid = threadIdx.x, w = tid>>6, l = tid&63, g = l>>4, c16 = l&15;
  for (int e=tid; e<2048; e+=256){ int key=e>>7, d=e&127; kad[key*136+d] = (key<4)? vdk[(h*4+key)*HDM+d] : (u16)0; }
  for (int e=tid; e<4096; e+=256){ int d=e>>5, key=e&31; vad[d*40+key]   = (key<4)? vdv[(h*4+key)*HDM+d] : (u16)0; }
  int qrow = qb + w*16 + c16;
  s16x8 qf[4];
  #pragma unroll
  for (int kc=0;kc<4;kc++) qf[kc] = *(const s16x8*)(qh + ((size_t)h*S_TOTC + qrow)*HDM + kc*32 + g*8);
  f32x4 acc[8];
  #pragma unroll
  for (int dt=0;dt<8;dt++) acc[dt] = f32x4{0.f,0.f,0.f,0.f};
  float m_[4] = {-3e38f,-3e38f,-3e38f,-3e38f};
  float l_[4] = {0.f,0.f,0.f,0.f};
  const float scl = 0.08838834764831845f;
  int srK = tid>>4, scK = (tid&15)*8;
  int srV = tid>>2, scV = (tid&3)*8;
  for (int kb=0; kb<S_TOTC; kb+=32){
    s16x8 kv0 = *(const s16x8*)(kh + ((size_t)h*S_TOTC + kb + srK)*HDM + scK);
    s16x8 kv1 = *(const s16x8*)(kh + ((size_t)h*S_TOTC + kb + 16 + srK)*HDM + scK);
    s16x8 vv0 = *(const s16x8*)(vt + ((size_t)h*HDM + srV)*S_TOTC + kb + scV);
    s16x8 vv1 = *(const s16x8*)(vt + ((size_t)h*HDM + 64 + srV)*S_TOTC + kb + scV);
    *(s16x8*)&kts[srK*136 + scK]      = kv0;
    *(s16x8*)&kts[(16+srK)*136 + scK] = kv1;
    *(s16x8*)&vts[srV*40 + scV]       = vv0;
    *(s16x8*)&vts[(64+srV)*40 + scV]  = vv1;
    __syncthreads();
    f32x4 s0 = {0.f,0.f,0.f,0.f}, s1 = {0.f,0.f,0.f,0.f};
    #pragma unroll
    for (int kc=0;kc<4;kc++){
      s16x8 kf0 = *(const s16x8*)&kts[c16*136 + (kc*4+g)*8];
      s16x8 kf1 = *(const s16x8*)&kts[(16+c16)*136 + (kc*4+g)*8];
      s0 = __builtin_amdgcn_mfma_f32_16x16x32_bf16(qf[kc], kf0, s0, 0,0,0);
      s1 = __builtin_amdgcn_mfma_f32_16x16x32_bf16(qf[kc], kf1, s1, 0,0,0);
    }
    float tm[4], corr[4], rs[4];
    #pragma unroll
    for (int r=0;r<4;r++){ s0[r]*=scl; s1[r]*=scl; tm[r] = fmaxf(s0[r], s1[r]); }
    #pragma unroll
    for (int m=1;m<16;m<<=1)
      #pragma unroll
      for (int r=0;r<4;r++) tm[r] = fmaxf(tm[r], __shfl_xor(tm[r], m));
    #pragma unroll
    for (int r=0;r<4;r++){
      float mn = fmaxf(m_[r], tm[r]);
      corr[r] = __expf(m_[r]-mn);
      m_[r] = mn;
      float p0 = __expf(s0[r]-mn), p1 = __expf(s1[r]-mn);
      s0[r]=p0; s1[r]=p1; rs[r] = p0+p1;
    }
    #pragma unroll
    for (int m=1;m<16;m<<=1)
      #pragma unroll
      for (int r=0;r<4;r++) rs[r] += __shfl_xor(rs[r], m);
    #pragma unroll
    for (int r=0;r<4;r++) l_[r] = l_[r]*corr[r] + rs[r];
    #pragma unroll
    for (int dt=0;dt<8;dt++)
      #pragma unroll
      for (int r=0;r<4;r++) acc[dt][r] *= corr[r];
    #pragma unroll
    for (int r=0;r<4;r++){
      pwb[(w*16 + g*4 + r)*40 + c16]      = f2b(s0[r]);
      pwb[(w*16 + g*4 + r)*40 + 16 + c16] = f2b(s1[r]);
    }
    s16x8 pf = *(const s16x8*)&pwb[(w*16 + c16)*40 + g*8];
    #pragma unroll
    for (int dt=0;dt<8;dt++){
      s16x8 vf = *(const s16x8*)&vts[(dt*16 + c16)*40 + g*8];
      acc[dt] = __builtin_amdgcn_mfma_f32_16x16x32_bf16(pf, vf, acc[dt], 0,0,0);
    }
    __syncthreads();
  }
  // adapter cross-attention: one masked tile (4 valid keys), separate stats
  f32x4 s2 = {0.f,0.f,0.f,0.f};
  #pragma unroll
  for (int kc=0;kc<4;kc++){
    s16x8 kf = *(const s16x8*)&kad[c16*136 + (kc*4+g)*8];
    s2 = __builtin_amdgcn_mfma_f32_16x16x32_bf16(qf[kc], kf, s2, 0,0,0);
  }
  bool valid = (c16 < 4);
  float m2[4], l2[4];
  #pragma unroll
  for (int r=0;r<4;r++){ s2[r]*=scl; m2[r] = valid? s2[r] : -3e38f; }
  #pragma unroll
  for (int m=1;m<16;m<<=1)
    #pragma unroll
    for (int r=0;r<4;r++) m2[r] = fmaxf(m2[r], __shfl_xor(m2[r], m));
  #pragma unroll
  for (int r=0;r<4;r++){ float p = valid? __expf(s2[r]-m2[r]) : 0.f; s2[r]=p; l2[r]=p; }
  #pragma unroll
  for (int m=1;m<16;m<<=1)
    #pragma unroll
    for (int r=0;r<4;r++) l2[r] += __shfl_xor(l2[r], m);
  #pragma unroll
  for (int r=0;r<4;r++){
    pwb[(w*16 + g*4 + r)*40 + c16]      = f2b(s2[r]);
    pwb[(w*16 + g*4 + r)*40 + 16 + c16] = (u16)0;
  }
  s16x8 pf2 = *(const s16x8*)&pwb[(w*16 + c16)*40 + g*8];
  f32x4 a2[8];
  #pragma unroll
  for (int dt=0;dt<8;dt++) a2[dt] = f32x4{0.f,0.f,0.f,0.f};
  #pragma unroll
  for (int dt=0;dt<8;dt++){
    s16x8 vf = *(const s16x8*)&vad[(dt*16 + c16)*40 + g*8];
    a2[dt] = __builtin_amdgcn_mfma_f32_16x16x32_bf16(pf2, vf, a2[dt], 0,0,0);
  }
  float sb = bscale[0];
  #pragma unroll
  for (int dt=0;dt<8;dt++)
    #pragma unroll
    for (int r=0;r<4;r++){
      int tok = qb + w*16 + g*4 + r;
      int col = h*HDM + dt*16 + c16;
      hs[(size_t)tok*DM + col] = acc[dt][r]/l_[r] + sb*(a2[dt][r]/l2[r]);
    }
}

extern "C" void kernel_launch(void* const* d_in, const int* in_sizes, int n_in,
                              void* d_out, int out_size, void* d_ws, size_t ws_size,
                              hipStream_t stream){
  static const int expect[28] = {
    6291456, 1572864, 4096, 327680, 327680,
    9437184, 3072, 9437184, 3072, 9437184, 3072, 128, 128,
    9437184, 3072, 9437184, 3072, 9437184, 3072, 128, 128,
    9437184, 3072, 9437184, 3072, 3145728, 3145728, 1 };
  bool ok = (n_in == 28);
  if (ok) for (int i=0;i<28;i++) if (in_sizes[i] != expect[i]) { ok = false; break; }
  if (!ok){
    fill7<<<(out_size+255)/256,256,0,stream>>>((float*)d_out, out_size);
    return;
  }

  const float* hidden = (const float*)d_in[0];
  const float* enc    = (const float*)d_in[1];
  const float* adapt  = (const float*)d_in[2];
  const float* fcos   = (const float*)d_in[3];
  const float* fsin   = (const float*)d_in[4];
  const float* Wq  = (const float*)d_in[5];  const float* bq  = (const float*)d_in[6];
  const float* Wk  = (const float*)d_in[7];  const float* bk  = (const float*)d_in[8];
  const float* Wv  = (const float*)d_in[9];  const float* bv  = (const float*)d_in[10];
  const float* nqw = (const float*)d_in[11]; const float* nkw = (const float*)d_in[12];
  const float* Wqa = (const float*)d_in[13]; const float* bqa = (const float*)d_in[14];
  const float* Wka = (const float*)d_in[15]; const float* bka = (const float*)d_in[16];
  const float* Wva = (const float*)d_in[17]; const float* bva = (const float*)d_in[18];
  const float* naq = (const float*)d_in[19]; const float* nak = (const float*)d_in[20];
  const float* Wo  = (const float*)d_in[21]; const float* bo  = (const float*)d_in[22];
  const float* Woa = (const float*)d_in[23]; const float* boa = (const float*)d_in[24];
  const float* Wkad = (const float*)d_in[25]; const float* Wvad = (const float*)d_in[26];
  const float* bsc  = (const float*)d_in[27];
  float* out = (float*)d_out;

  // ws layout (bytes), peak ~113 MB
  char* ws = (char*)d_ws;
  u16* wt   = (u16*)(ws);                 // 18,874,368 B (3072x3072 bf16)
  u16* qri  = (u16*)(ws + 18874368);      // 12,582,912 each (2048x3072 bf16)
  u16* kri  = (u16*)(ws + 31457280);
  u16* vri  = (u16*)(ws + 44040192);
  u16* qrt  = (u16*)(ws + 56623104);      // 3,145,728 each (512x3072 bf16)
  u16* krt  = (u16*)(ws + 59768832);
  u16* vrt  = (u16*)(ws + 62914560);
  u16* qh   = (u16*)(ws + 66060288);      // 15,728,640 each (24x2560x128 bf16)
  u16* kh   = (u16*)(ws + 81788928);
  u16* vth  = (u16*)(ws + 97517568);      // ends 113,246,208
  u16*   vdk = (u16*)(ws + 62914560);     // vrt slot (dead after epi_v)
  u16*   vdv = (u16*)(ws + 62939136);
  float* hsb = (float*)(ws + 18874368);   // fp32 2560x3072 = 31,457,280 B (qri/kri region, dead at attnk)

  dim3 tg(48,48);
  ktrans<<<tg,256,0,stream>>>(Wq, wt);
  gemm128<0><<<dim3(16,24),256,0,stream>>>(hidden, wt, bq, qri);
  ktrans<<<tg,256,0,stream>>>(Wk, wt);
  gemm128<0><<<dim3(16,24),256,0,stream>>>(hidden, wt, bk, kri);
  ktrans<<<tg,256,0,stream>>>(Wv, wt);
  gemm128<0><<<dim3(16,24),256,0,stream>>>(hidden, wt, bv, vri);
  ktrans<<<tg,256,0,stream>>>(Wqa, wt);
  gemm128<0><<<dim3(4,24),256,0,stream>>>(enc, wt, bqa, qrt);
  ktrans<<<tg,256,0,stream>>>(Wka, wt);
  gemm128<0><<<dim3(4,24),256,0,stream>>>(enc, wt, bka, krt);
  ktrans<<<tg,256,0,stream>>>(Wva, wt);
  gemm128<0><<<dim3(4,24),256,0,stream>>>(enc, wt, bva, vrt);
  epi_qk<<<30720,256,0,stream>>>(qri,qrt,kri,krt,nqw,nkw,naq,nak,fcos,fsin,qh,kh);
  epi_v<<<24*40,256,0,stream>>>(vri,vrt,vth);
  adapterk<<<6144,256,0,stream>>>(adapt, Wkad, Wvad, vdk, vdv);
  attnk<<<dim3(40,24),256,0,stream>>>(qh,kh,vth,vdk,vdv,bsc,hsb);
  ktrans<<<tg,256,0,stream>>>(Woa, wt);
  gemm128<1><<<dim3(4,24),256,0,stream>>>(hsb, wt, boa, out + (size_t)2048*3072);
  ktrans<<<tg,256,0,stream>>>(Wo, wt);
  gemm128<1><<<dim3(16,24),256,0,stream>>>(hsb + (size_t)512*3072, wt, bo, out);
}

// Round 8
// 780.744 us; speedup vs baseline: 8.8372x; 1.7548x over previous
//
#include <hip/hip_runtime.h>

typedef unsigned short u16;
typedef short s16x8 __attribute__((ext_vector_type(8)));
typedef float f32x4 __attribute__((ext_vector_type(4)));

#define S_TXTC 512
#define S_TOTC 2560
#define DM 3072
#define NH 24
#define HDM 128

__device__ __forceinline__ float b2f(u16 u){ unsigned int i = ((unsigned int)u)<<16; float f; __builtin_memcpy(&f,&i,4); return f; }
__device__ __forceinline__ u16 f2b(float f){ unsigned int i; __builtin_memcpy(&i,&f,4); unsigned int r = i + 0x7FFFu + ((i>>16)&1u); return (u16)(r>>16); }
__device__ __forceinline__ s16x8 pk8(float4 a, float4 b){
  s16x8 r;
  r[0]=(short)f2b(a.x); r[1]=(short)f2b(a.y); r[2]=(short)f2b(a.z); r[3]=(short)f2b(a.w);
  r[4]=(short)f2b(b.x); r[5]=(short)f2b(b.y); r[6]=(short)f2b(b.z); r[7]=(short)f2b(b.w);
  return r;
}
__device__ __forceinline__ void g2l16(const void* g, void* l){
  __builtin_amdgcn_global_load_lds((const __attribute__((address_space(1))) void*)g,
                                   (__attribute__((address_space(3))) void*)l, 16, 0, 0);
}

__global__ __launch_bounds__(256) void fillv(float* __restrict__ p, int n, float v){
  int i = blockIdx.x*256 + threadIdx.x;
  if (i < n) p[i] = v;
}

// ---------------- cast fp32 -> bf16, 8 elems/thread ----------------
__global__ __launch_bounds__(256) void cast_bf(const float* __restrict__ src, u16* __restrict__ dst, int n8){
  int i = blockIdx.x*256 + threadIdx.x;
  if (i < n8){
    float4 a = *(const float4*)(src + (size_t)i*8);
    float4 b = *(const float4*)(src + (size_t)i*8 + 4);
    *(s16x8*)(dst + (size_t)i*8) = pk8(a,b);
  }
}

// ---------------- concat 3 biases (3072 each) into 9216 fp32 ----------------
__global__ __launch_bounds__(256) void catbias(const float* __restrict__ b0, const float* __restrict__ b1,
                                               const float* __restrict__ b2, float* __restrict__ dst){
  int i = blockIdx.x*256 + threadIdx.x;
  if (i < 9216) dst[i] = (i<3072)? b0[i] : (i<6144? b1[i-3072] : b2[i-6144]);
}

// ---------------- transpose+cast 3072x3072: Wt_bf16[n][k] = W_f32[k][n] ----------------
__global__ __launch_bounds__(256) void ktrans(const float* __restrict__ W, u16* __restrict__ Wt){
  __shared__ __align__(16) u16 t[64*72];
  int nt = blockIdx.x*64, kt_ = blockIdx.y*64;
  int tid = threadIdx.x;
  #pragma unroll
  for (int i=0;i<2;i++){
    int q = tid + 256*i;
    int r = q>>3, c8 = (q&7)*8;
    float4 f0 = *(const float4*)(W + (size_t)(kt_+r)*DM + nt + c8);
    float4 f1 = *(const float4*)(W + (size_t)(kt_+r)*DM + nt + c8 + 4);
    *(s16x8*)&t[r*72 + c8] = pk8(f0,f1);
  }
  __syncthreads();
  #pragma unroll
  for (int i=0;i<2;i++){
    int q = tid + 256*i;
    int n = q>>3, k8 = (q&7)*8;
    s16x8 v;
    #pragma unroll
    for (int j=0;j<8;j++) v[j] = (short)t[(k8+j)*72 + n];
    *(s16x8*)(Wt + (size_t)(nt+n)*DM + kt_ + k8) = v;
  }
}

// ---------------- m97-style bf16 GEMM core: C[m][n] = sum_k A[m][k]*Bt[n][k] + bias[n] ----------------
// 128x128 tile, 4 waves, BK=32, global_load_lds(16B) staging, linear LDS [128][32]
template<int OUT32>
__device__ __forceinline__ void gcore(u16* la, u16* lb,
    const u16* __restrict__ A, const u16* __restrict__ Bt,
    const float* __restrict__ bias, void* __restrict__ Cv,
    int ldc, int rb, int crb, int cb){
  const int K = DM;
  int tid = threadIdx.x, w = tid>>6, l = tid&63, g = l>>4, c16 = l&15;
  int wr = (w>>1)*64, wc = (w&1)*64;
  f32x4 acc[4][4] = {};
  const u16* aL = A  + (size_t)(rb + w*32 + (l>>2))*K + (l&3)*8;
  const u16* bL = Bt + (size_t)(cb + w*32 + (l>>2))*K + (l&3)*8;
  u16* laB = la + w*1024;
  u16* lbB = lb + w*1024;
  for (int ks=0; ks<K; ks+=32){
    g2l16(aL + ks,              laB);
    g2l16(aL + 16*(size_t)K + ks, laB + 512);
    g2l16(bL + ks,              lbB);
    g2l16(bL + 16*(size_t)K + ks, lbB + 512);
    __syncthreads();
    s16x8 af[4], bf[4];
    #pragma unroll
    for (int m=0;m<4;m++) af[m] = *(const s16x8*)&la[(wr + m*16 + c16)*32 + g*8];
    #pragma unroll
    for (int n=0;n<4;n++) bf[n] = *(const s16x8*)&lb[(wc + n*16 + c16)*32 + g*8];
    #pragma unroll
    for (int m=0;m<4;m++)
      #pragma unroll
      for (int n=0;n<4;n++)
        acc[m][n] = __builtin_amdgcn_mfma_f32_16x16x32_bf16(af[m], bf[n], acc[m][n], 0,0,0);
    __syncthreads();
  }
  #pragma unroll
  for (int n=0;n<4;n++){
    int col = cb + wc + n*16 + c16;
    float bv = bias[col];
    #pragma unroll
    for (int m=0;m<4;m++){
      int r0 = crb + wr + m*16 + g*4;
      #pragma unroll
      for (int r=0;r<4;r++){
        float oo = acc[m][n][r] + bv;
        if (OUT32) ((float*)Cv)[(size_t)(r0+r)*ldc + col] = oo;
        else       ((u16*)Cv)[(size_t)(r0+r)*ldc + col] = f2b(oo);
      }
    }
  }
}

__global__ __launch_bounds__(256) void qkv_gemm(const u16* __restrict__ A, const u16* __restrict__ Bt,
                                                const float* __restrict__ bias, u16* __restrict__ C){
  __shared__ __align__(16) u16 la[4096];
  __shared__ __align__(16) u16 lb[4096];
  gcore<0>(la, lb, A, Bt, bias, C, 3*DM, blockIdx.x*128, blockIdx.x*128, blockIdx.y*128);
}

__global__ __launch_bounds__(256) void out_gemm(const u16* __restrict__ hsb,
    const u16* __restrict__ woT, const u16* __restrict__ woaT,
    const float* __restrict__ bo, const float* __restrict__ boa, float* __restrict__ out){
  __shared__ __align__(16) u16 la[4096];
  __shared__ __align__(16) u16 lb[4096];
  int bx = blockIdx.x;
  bool txt = (bx < 4);
  int rb = bx*128;
  const u16* Bt = txt? woaT : woT;
  const float* bias = txt? boa : bo;
  float* dst = txt? out + (size_t)2048*DM : out;
  int crb = txt? rb : rb - 512;
  gcore<1>(la, lb, hsb, Bt, bias, dst, DM, rb, crb, blockIdx.y*128);
}

// ---------------- epilogue q,k: per-head RMSNorm + RoPE, gather to [H][S_TOT][HD] (bf16) ----------------
__global__ __launch_bounds__(256) void epi_qk(
    const u16* __restrict__ qkvI, const u16* __restrict__ qkvT,
    const float* __restrict__ nqw, const float* __restrict__ nkw,
    const float* __restrict__ naq, const float* __restrict__ nak,
    const float* __restrict__ fcos, const float* __restrict__ fsin,
    u16* __restrict__ qh, u16* __restrict__ kh){
  int wid = blockIdx.x*4 + (threadIdx.x>>6);
  int lane = threadIdx.x&63;
  int which = wid / (NH*S_TOTC);
  int rem = wid % (NH*S_TOTC);
  int h = rem / S_TOTC, tok = rem % S_TOTC;
  const u16* src = ((tok<S_TXTC)? qkvT + (size_t)tok*(3*DM) : qkvI + (size_t)(tok-S_TXTC)*(3*DM))
                   + which*DM + h*HDM;
  const float* nw = which? ((tok<S_TXTC)? nak : nkw) : ((tok<S_TXTC)? naq : nqw);
  int d = lane*2;
  unsigned int u = *(const unsigned int*)(src + d);
  float x0 = b2f((u16)(u&0xffffu)), x1 = b2f((u16)(u>>16));
  float ss = x0*x0 + x1*x1;
  #pragma unroll
  for (int m=1;m<64;m<<=1) ss += __shfl_xor(ss, m);
  float rr = rsqrtf(ss*(1.f/128.f) + 1e-6f);
  float y0 = x0*rr*nw[d];
  float y1 = x1*rr*nw[d+1];
  float2 cc = *(const float2*)(fcos + (size_t)tok*HDM + d);
  float2 sn = *(const float2*)(fsin + (size_t)tok*HDM + d);
  float o0 = y0*cc.x - y1*sn.x;
  float o1 = y1*cc.y + y0*sn.y;
  u16* dst = (which? kh : qh) + ((size_t)h*S_TOTC + tok)*HDM + d;
  *(unsigned int*)dst = (unsigned int)f2b(o0) | ((unsigned int)f2b(o1)<<16);
}

// ---------------- epilogue v: gather + transpose to v_t[H][HD][S_TOT] (bf16) ----------------
__global__ __launch_bounds__(256) void epi_v(const u16* __restrict__ qkvI, const u16* __restrict__ qkvT,
                                             u16* __restrict__ vt){
  __shared__ __align__(16) u16 t[64*136];
  int h = blockIdx.x % NH, tb = blockIdx.x / NH;
  int tok0 = tb*64, tid = threadIdx.x;
  #pragma unroll
  for (int i=0;i<4;i++){
    int q = tid + 256*i;
    int tr = q>>4, c8 = (q&15)*8;
    int tok = tok0 + tr;
    const u16* src = ((tok<S_TXTC)? qkvT + (size_t)tok*(3*DM) : qkvI + (size_t)(tok-S_TXTC)*(3*DM))
                     + 2*DM + h*HDM;
    *(s16x8*)&t[tr*136 + c8] = *(const s16x8*)(src + c8);
  }
  __syncthreads();
  #pragma unroll
  for (int i=0;i<4;i++){
    int q = tid + 256*i;
    int d = q>>3, j8 = (q&7)*8;
    s16x8 v;
    #pragma unroll
    for (int j=0;j<8;j++) v[j] = (short)t[(j8+j)*136 + d];
    *(s16x8*)(vt + ((size_t)h*HDM + d)*S_TOTC + tok0 + j8) = v;
  }
}

// ---------------- adapter projections: f32 (4x1024)@(1024x3072) -> bf16 [H][4][HD] ----------------
__global__ __launch_bounds__(256) void adapterk(const float* __restrict__ ad, const float* __restrict__ Wk,
        const float* __restrict__ Wv, u16* __restrict__ vdk, u16* __restrict__ vdv){
  int wid = blockIdx.x*4 + (threadIdx.x>>6);
  int lane = threadIdx.x&63;
  int tensor = wid / (4*DM);
  int rem = wid % (4*DM);
  int tok = rem / DM, col = rem % DM;
  const float* Wp = tensor? Wv : Wk;
  float s = 0.f;
  #pragma unroll
  for (int i=0;i<16;i++){
    int k = lane + 64*i;
    s += ad[tok*1024 + k] * Wp[(size_t)k*DM + col];
  }
  #pragma unroll
  for (int m=1;m<64;m<<=1) s += __shfl_xor(s, m);
  if (lane==0){
    int hh = col>>7, d = col&127;
    (tensor? vdv : vdk)[(hh*4+tok)*HDM + d] = f2b(s);
  }
}

// ---------------- fused MFMA flash attention, KVBLK=64, reg-dbuf prefetch, bf16 out ----------------
__global__ __launch_bounds__(256) void attnk(const u16* __restrict__ qh, const u16* __restrict__ kh,
    const u16* __restrict__ vt, const u16* __restrict__ vdk, const u16* __restrict__ vdv,
    const float* __restrict__ bscale, u16* __restrict__ hs){
  __shared__ __align__(16) u16 kts[64*136];   // [key][d] stride 136
  __shared__ __align__(16) u16 vts[128*72];   // [d][key] stride 72
  __shared__ __align__(16) u16 pwb[64*72];    // [q][key] stride 72
  __shared__ __align__(16) u16 kad[16*136];
  __shared__ __align__(16) u16 vad[128*40];
  int h = blockIdx.y, qb = blockIdx.x*64;
  int tid = threadIdx.x, w = tid>>6, l = tid&63, g = l>>4, c16 = l&15;
  for (int e=tid; e<2048; e+=256){ int key=e>>7, d=e&127; kad[key*136+d] = (key<4)? vdk[(h*4+key)*HDM+d] : (u16)0; }
  for (int e=tid; e<4096; e+=256){ int d=e>>5, key=e&31; vad[d*40+key]   = (key<4)? vdv[(h*4+key)*HDM+d] : (u16)0; }
  int qrow = qb + w*16 + c16;
  s16x8 qf[4];
  #pragma unroll
  for (int kc=0;kc<4;kc++) qf[kc] = *(const s16x8*)(qh + ((size_t)h*S_TOTC + qrow)*HDM + kc*32 + g*8);
  f32x4 acc[8];
  #pragma unroll
  for (int dt=0;dt<8;dt++) acc[dt] = f32x4{0.f,0.f,0.f,0.f};
  float m_[4] = {-3e38f,-3e38f,-3e38f,-3e38f};
  float l_[4] = {0.f,0.f,0.f,0.f};
  const float scl = 0.08838834764831845f;
  const u16* khB = kh + (size_t)h*S_TOTC*HDM;
  const u16* vtB = vt + (size_t)h*HDM*S_TOTC;

  auto LOADT = [&](s16x8* kr, s16x8* vr, int kb){
    #pragma unroll
    for (int i=0;i<4;i++){
      int idx = tid + 256*i;
      kr[i] = *(const s16x8*)(khB + (size_t)(kb + (idx>>4))*HDM + (idx&15)*8);
      vr[i] = *(const s16x8*)(vtB + (size_t)(idx>>3)*S_TOTC + kb + (idx&7)*8);
    }
  };
  auto STORET = [&](s16x8* kr, s16x8* vr){
    #pragma unroll
    for (int i=0;i<4;i++){
      int idx = tid + 256*i;
      *(s16x8*)&kts[(idx>>4)*136 + (idx&15)*8] = kr[i];
      *(s16x8*)&vts[(idx>>3)*72 + (idx&7)*8] = vr[i];
    }
  };
  auto COMPUTE = [&](){
    f32x4 s[4];
    #pragma unroll
    for (int su=0;su<4;su++) s[su] = f32x4{0.f,0.f,0.f,0.f};
    __builtin_amdgcn_s_setprio(1);
    #pragma unroll
    for (int su=0;su<4;su++)
      #pragma unroll
      for (int kc=0;kc<4;kc++){
        s16x8 kf = *(const s16x8*)&kts[(su*16+c16)*136 + (kc*4+g)*8];
        s[su] = __builtin_amdgcn_mfma_f32_16x16x32_bf16(qf[kc], kf, s[su], 0,0,0);
      }
    __builtin_amdgcn_s_setprio(0);
    float tm[4], corr[4], rs[4];
    #pragma unroll
    for (int r=0;r<4;r++){
      #pragma unroll
      for (int su=0;su<4;su++) s[su][r] *= scl;
      tm[r] = fmaxf(fmaxf(s[0][r],s[1][r]), fmaxf(s[2][r],s[3][r]));
    }
    #pragma unroll
    for (int m=1;m<16;m<<=1)
      #pragma unroll
      for (int r=0;r<4;r++) tm[r] = fmaxf(tm[r], __shfl_xor(tm[r], m));
    #pragma unroll
    for (int r=0;r<4;r++){
      float mn = fmaxf(m_[r], tm[r]);
      corr[r] = __expf(m_[r]-mn);
      m_[r] = mn;
      rs[r] = 0.f;
      #pragma unroll
      for (int su=0;su<4;su++){ s[su][r] = __expf(s[su][r]-mn); rs[r] += s[su][r]; }
    }
    #pragma unroll
    for (int m=1;m<16;m<<=1)
      #pragma unroll
      for (int r=0;r<4;r++) rs[r] += __shfl_xor(rs[r], m);
    #pragma unroll
    for (int r=0;r<4;r++) l_[r] = l_[r]*corr[r] + rs[r];
    #pragma unroll
    for (int dt=0;dt<8;dt++)
      #pragma unroll
      for (int r=0;r<4;r++) acc[dt][r] *= corr[r];
    #pragma unroll
    for (int su=0;su<4;su++)
      #pragma unroll
      for (int r=0;r<4;r++)
        pwb[(w*16 + g*4 + r)*72 + su*16 + c16] = f2b(s[su][r]);
    s16x8 pf0 = *(const s16x8*)&pwb[(w*16 + c16)*72 + g*8];
    s16x8 pf1 = *(const s16x8*)&pwb[(w*16 + c16)*72 + 32 + g*8];
    __builtin_amdgcn_s_setprio(1);
    #pragma unroll
    for (int dt=0;dt<8;dt++){
      s16x8 vf0 = *(const s16x8*)&vts[(dt*16 + c16)*72 + g*8];
      acc[dt] = __builtin_amdgcn_mfma_f32_16x16x32_bf16(pf0, vf0, acc[dt], 0,0,0);
      s16x8 vf1 = *(const s16x8*)&vts[(dt*16 + c16)*72 + 32 + g*8];
      acc[dt] = __builtin_amdgcn_mfma_f32_16x16x32_bf16(pf1, vf1, acc[dt], 0,0,0);
    }
    __builtin_amdgcn_s_setprio(0);
  };

  s16x8 ka[4], va[4], kb2[4], vb2[4];
  LOADT(ka, va, 0);
  for (int kb=0; kb<S_TOTC; kb+=128){
    STORET(ka, va);
    __syncthreads();
    LOADT(kb2, vb2, kb+64);
    COMPUTE();
    __syncthreads();
    STORET(kb2, vb2);
    __syncthreads();
    if (kb+128 < S_TOTC) LOADT(ka, va, kb+128);
    COMPUTE();
    __syncthreads();
  }

  // adapter cross-attention: one masked 16-key tile (4 valid), separate stats
  f32x4 s2 = {0.f,0.f,0.f,0.f};
  #pragma unroll
  for (int kc=0;kc<4;kc++){
    s16x8 kf = *(const s16x8*)&kad[c16*136 + (kc*4+g)*8];
    s2 = __builtin_amdgcn_mfma_f32_16x16x32_bf16(qf[kc], kf, s2, 0,0,0);
  }
  bool valid = (c16 < 4);
  float m2[4], l2[4];
  #pragma unroll
  for (int r=0;r<4;r++){ s2[r]*=scl; m2[r] = valid? s2[r] : -3e38f; }
  #pragma unroll
  for (int m=1;m<16;m<<=1)
    #pragma unroll
    for (int r=0;r<4;r++) m2[r] = fmaxf(m2[r], __shfl_xor(m2[r], m));
  #pragma unroll
  for (int r=0;r<4;r++){ float p = valid? __expf(s2[r]-m2[r]) : 0.f; s2[r]=p; l2[r]=p; }
  #pragma unroll
  for (int m=1;m<16;m<<=1)
    #pragma unroll
    for (int r=0;r<4;r++) l2[r] += __shfl_xor(l2[r], m);
  #pragma unroll
  for (int r=0;r<4;r++){
    pwb[(w*16 + g*4 + r)*72 + c16]      = f2b(s2[r]);
    pwb[(w*16 + g*4 + r)*72 + 16 + c16] = (u16)0;
  }
  s16x8 pf2 = *(const s16x8*)&pwb[(w*16 + c16)*72 + g*8];
  f32x4 a2[8];
  #pragma unroll
  for (int dt=0;dt<8;dt++) a2[dt] = f32x4{0.f,0.f,0.f,0.f};
  #pragma unroll
  for (int dt=0;dt<8;dt++){
    s16x8 vf = *(const s16x8*)&vad[(dt*16 + c16)*40 + g*8];
    a2[dt] = __builtin_amdgcn_mfma_f32_16x16x32_bf16(pf2, vf, a2[dt], 0,0,0);
  }
  float sb = bscale[0];
  #pragma unroll
  for (int dt=0;dt<8;dt++)
    #pragma unroll
    for (int r=0;r<4;r++){
      int tok = qb + w*16 + g*4 + r;
      int col = h*HDM + dt*16 + c16;
      hs[(size_t)tok*DM + col] = f2b(acc[dt][r]/l_[r] + sb*(a2[dt][r]/l2[r]));
    }
}

extern "C" void kernel_launch(void* const* d_in, const int* in_sizes, int n_in,
                              void* d_out, int out_size, void* d_ws, size_t ws_size,
                              hipStream_t stream){
  static const int expect[28] = {
    6291456, 1572864, 4096, 327680, 327680,
    9437184, 3072, 9437184, 3072, 9437184, 3072, 128, 128,
    9437184, 3072, 9437184, 3072, 9437184, 3072, 128, 128,
    9437184, 3072, 9437184, 3072, 3145728, 3145728, 1 };
  bool ok = (n_in == 28);
  if (ok) for (int i=0;i<28;i++) if (in_sizes[i] != expect[i]) { ok = false; break; }
  if (!ok){ fillv<<<(out_size+255)/256,256,0,stream>>>((float*)d_out, out_size, 7.0f); return; }
  if (ws_size < 119611392ull){ fillv<<<(out_size+255)/256,256,0,stream>>>((float*)d_out, out_size, 9.0f); return; }

  const float* hidden = (const float*)d_in[0];
  const float* enc    = (const float*)d_in[1];
  const float* adapt  = (const float*)d_in[2];
  const float* fcos   = (const float*)d_in[3];
  const float* fsin   = (const float*)d_in[4];
  const float* Wq  = (const float*)d_in[5];  const float* bq  = (const float*)d_in[6];
  const float* Wk  = (const float*)d_in[7];  const float* bk  = (const float*)d_in[8];
  const float* Wv  = (const float*)d_in[9];  const float* bv  = (const float*)d_in[10];
  const float* nqw = (const float*)d_in[11]; const float* nkw = (const float*)d_in[12];
  const float* Wqa = (const float*)d_in[13]; const float* bqa = (const float*)d_in[14];
  const float* Wka = (const float*)d_in[15]; const float* bka = (const float*)d_in[16];
  const float* Wva = (const float*)d_in[17]; const float* bva = (const float*)d_in[18];
  const float* naq = (const float*)d_in[19]; const float* nak = (const float*)d_in[20];
  const float* Wo  = (const float*)d_in[21]; const float* bo  = (const float*)d_in[22];
  const float* Woa = (const float*)d_in[23]; const float* boa = (const float*)d_in[24];
  const float* Wkad = (const float*)d_in[25]; const float* Wvad = (const float*)d_in[26];
  const float* bsc  = (const float*)d_in[27];
  float* out = (float*)d_out;

  // ws layout (bytes), peak ~119.6 MB with lifetime overlap
  char* ws = (char*)d_ws;
  u16* wt3   = (u16*)(ws);                  // [0, 56,623,104): 3 transposed weights [9216][3072]
  u16* kh    = (u16*)(ws);                  //   after qkv gemms: kh (15,728,640)
  u16* vth   = (u16*)(ws + 15728640);       //   vth (15,728,640)
  u16* vdk   = (u16*)(ws + 31457280);       //   vdk/vdv (24,576 each)
  u16* vdv   = (u16*)(ws + 31481856);
  u16* woaT  = (u16*)(ws + 33554432);       //   Woa^T (18,874,368) after attnk
  u16* hbf   = (u16*)(ws + 56623104);       // [56.6M, 72.35M): hidden bf16 (12,582,912)
  u16* ebf   = (u16*)(ws + 69206016);       //   enc bf16 (3,145,728)
  u16* qh    = (u16*)(ws + 56623104);       //   after txt gemm: qh (15,728,640)
  u16* qkvI  = (u16*)(ws + 72351744);       // [72.35M, 110.1M): img QKV [2048][9216]
  u16* hsb   = (u16*)(ws + 72351744);       //   after epi: hsb bf16 [2560][3072]
  u16* woT   = (u16*)(ws + 88080384);       //   Wo^T (18,874,368) after attnk
  u16* qkvT  = (u16*)(ws + 110100480);      // [110.1M, 119.54M): txt QKV [512][9216]
  float* biasA = (float*)(ws + 119537664);  // 9216 fp32
  float* biasB = (float*)(ws + 119574528);

  dim3 tg(48,48);
  cast_bf<<<3072,256,0,stream>>>(hidden, hbf, 786432);
  cast_bf<<<768,256,0,stream>>>(enc, ebf, 196608);
  catbias<<<36,256,0,stream>>>(bq, bk, bv, biasA);
  catbias<<<36,256,0,stream>>>(bqa, bka, bva, biasB);
  // img QKV
  ktrans<<<tg,256,0,stream>>>(Wq, wt3);
  ktrans<<<tg,256,0,stream>>>(Wk, wt3 + (size_t)DM*DM);
  ktrans<<<tg,256,0,stream>>>(Wv, wt3 + (size_t)2*DM*DM);
  qkv_gemm<<<dim3(16,72),256,0,stream>>>(hbf, wt3, biasA, qkvI);
  // txt QKV (reuse wt3)
  ktrans<<<tg,256,0,stream>>>(Wqa, wt3);
  ktrans<<<tg,256,0,stream>>>(Wka, wt3 + (size_t)DM*DM);
  ktrans<<<tg,256,0,stream>>>(Wva, wt3 + (size_t)2*DM*DM);
  qkv_gemm<<<dim3(4,72),256,0,stream>>>(ebf, wt3, biasB, qkvT);
  // epilogues + adapter
  epi_qk<<<30720,256,0,stream>>>(qkvI, qkvT, nqw,nkw,naq,nak, fcos,fsin, qh, kh);
  epi_v<<<24*40,256,0,stream>>>(qkvI, qkvT, vth);
  adapterk<<<6144,256,0,stream>>>(adapt, Wkad, Wvad, vdk, vdv);
  // attention -> bf16 hsb
  attnk<<<dim3(40,24),256,0,stream>>>(qh, kh, vth, vdk, vdv, bsc, hsb);
  // output projections (fused text+img)
  ktrans<<<tg,256,0,stream>>>(Wo, woT);
  ktrans<<<tg,256,0,stream>>>(Woa, woaT);
  out_gemm<<<dim3(20,24),256,0,stream>>>(hsb, woT, woaT, bo, boa, out);
}

// Round 9
// 747.751 us; speedup vs baseline: 9.2271x; 1.0441x over previous
//
#include <hip/hip_runtime.h>

typedef unsigned short u16;
typedef short s16x8 __attribute__((ext_vector_type(8)));
typedef float f32x4 __attribute__((ext_vector_type(4)));

#define S_TXTC 512
#define S_TOTC 2560
#define DM 3072
#define NH 24
#define HDM 128

__device__ __forceinline__ float b2f(u16 u){ unsigned int i = ((unsigned int)u)<<16; float f; __builtin_memcpy(&f,&i,4); return f; }
__device__ __forceinline__ u16 f2b(float f){ unsigned int i; __builtin_memcpy(&i,&f,4); unsigned int r = i + 0x7FFFu + ((i>>16)&1u); return (u16)(r>>16); }
__device__ __forceinline__ s16x8 pk8(float4 a, float4 b){
  s16x8 r;
  r[0]=(short)f2b(a.x); r[1]=(short)f2b(a.y); r[2]=(short)f2b(a.z); r[3]=(short)f2b(a.w);
  r[4]=(short)f2b(b.x); r[5]=(short)f2b(b.y); r[6]=(short)f2b(b.z); r[7]=(short)f2b(b.w);
  return r;
}
__device__ __forceinline__ void g2l16(const void* g, void* l){
  __builtin_amdgcn_global_load_lds((const __attribute__((address_space(1))) void*)g,
                                   (__attribute__((address_space(3))) void*)l, 16, 0, 0);
}

__global__ __launch_bounds__(256) void fillv(float* __restrict__ p, int n, float v){
  int i = blockIdx.x*256 + threadIdx.x;
  if (i < n) p[i] = v;
}

// ---------------- cast hidden+enc fp32 -> bf16 (contiguous dest) ----------------
__global__ __launch_bounds__(256) void cast2(const float* __restrict__ a, const float* __restrict__ b,
                                             u16* __restrict__ dst, int na8, int n8){
  int i = blockIdx.x*256 + threadIdx.x;
  if (i >= n8) return;
  const float* src = (i < na8)? a + (size_t)i*8 : b + (size_t)(i-na8)*8;
  float4 f0 = *(const float4*)src;
  float4 f1 = *(const float4*)(src+4);
  *(s16x8*)(dst + (size_t)i*8) = pk8(f0,f1);
}

// ---------------- concat 2x3 biases into 2x9216 fp32 (contiguous dest) ----------------
__global__ __launch_bounds__(256) void catbias2(const float* __restrict__ b0, const float* __restrict__ b1,
    const float* __restrict__ b2, const float* __restrict__ c0, const float* __restrict__ c1,
    const float* __restrict__ c2, float* __restrict__ dst){
  int i = blockIdx.x*256 + threadIdx.x;
  if (i >= 18432) return;
  int j = (i < 9216)? i : i - 9216;
  const float* s0 = (i<9216)? b0 : c0; const float* s1 = (i<9216)? b1 : c1; const float* s2 = (i<9216)? b2 : c2;
  dst[i] = (j<3072)? s0[j] : (j<6144? s1[j-3072] : s2[j-6144]);
}

// ---------------- transpose+cast up to 3 weights: Wt_bf16[n][k] = W_f32[k][n] ----------------
__global__ __launch_bounds__(256) void ktrans3(const float* __restrict__ W0, const float* __restrict__ W1,
    const float* __restrict__ W2, u16* __restrict__ D0, u16* __restrict__ D1, u16* __restrict__ D2){
  const float* W = (blockIdx.z==0)? W0 : ((blockIdx.z==1)? W1 : W2);
  u16* Wt = (blockIdx.z==0)? D0 : ((blockIdx.z==1)? D1 : D2);
  __shared__ __align__(16) u16 t[64*72];
  int nt = blockIdx.x*64, kt_ = blockIdx.y*64;
  int tid = threadIdx.x;
  #pragma unroll
  for (int i=0;i<2;i++){
    int q = tid + 256*i;
    int r = q>>3, c8 = (q&7)*8;
    float4 f0 = *(const float4*)(W + (size_t)(kt_+r)*DM + nt + c8);
    float4 f1 = *(const float4*)(W + (size_t)(kt_+r)*DM + nt + c8 + 4);
    *(s16x8*)&t[r*72 + c8] = pk8(f0,f1);
  }
  __syncthreads();
  #pragma unroll
  for (int i=0;i<2;i++){
    int q = tid + 256*i;
    int n = q>>3, k8 = (q&7)*8;
    s16x8 v;
    #pragma unroll
    for (int j=0;j<8;j++) v[j] = (short)t[(k8+j)*72 + n];
    *(s16x8*)(Wt + (size_t)(nt+n)*DM + kt_ + k8) = v;
  }
}

// ---------------- m97-style bf16 GEMM core ----------------
template<int OUT32>
__device__ __forceinline__ void gcore(u16* la, u16* lb,
    const u16* __restrict__ A, const u16* __restrict__ Bt,
    const float* __restrict__ bias, void* __restrict__ Cv,
    int ldc, int rb, int crb, int cb){
  const int K = DM;
  int tid = threadIdx.x, w = tid>>6, l = tid&63, g = l>>4, c16 = l&15;
  int wr = (w>>1)*64, wc = (w&1)*64;
  f32x4 acc[4][4] = {};
  const u16* aL = A  + (size_t)(rb + w*32 + (l>>2))*K + (l&3)*8;
  const u16* bL = Bt + (size_t)(cb + w*32 + (l>>2))*K + (l&3)*8;
  u16* laB = la + w*1024;
  u16* lbB = lb + w*1024;
  for (int ks=0; ks<K; ks+=32){
    g2l16(aL + ks,                laB);
    g2l16(aL + 16*(size_t)K + ks, laB + 512);
    g2l16(bL + ks,                lbB);
    g2l16(bL + 16*(size_t)K + ks, lbB + 512);
    __syncthreads();
    s16x8 af[4], bf[4];
    #pragma unroll
    for (int m=0;m<4;m++) af[m] = *(const s16x8*)&la[(wr + m*16 + c16)*32 + g*8];
    #pragma unroll
    for (int n=0;n<4;n++) bf[n] = *(const s16x8*)&lb[(wc + n*16 + c16)*32 + g*8];
    #pragma unroll
    for (int m=0;m<4;m++)
      #pragma unroll
      for (int n=0;n<4;n++)
        acc[m][n] = __builtin_amdgcn_mfma_f32_16x16x32_bf16(af[m], bf[n], acc[m][n], 0,0,0);
    __syncthreads();
  }
  #pragma unroll
  for (int n=0;n<4;n++){
    int col = cb + wc + n*16 + c16;
    float bv = bias[col];
    #pragma unroll
    for (int m=0;m<4;m++){
      int r0 = crb + wr + m*16 + g*4;
      #pragma unroll
      for (int r=0;r<4;r++){
        float oo = acc[m][n][r] + bv;
        if (OUT32) ((float*)Cv)[(size_t)(r0+r)*ldc + col] = oo;
        else       ((u16*)Cv)[(size_t)(r0+r)*ldc + col] = f2b(oo);
      }
    }
  }
}

__global__ __launch_bounds__(256) void qkv_gemm(const u16* __restrict__ A, const u16* __restrict__ Bt,
                                                const float* __restrict__ bias, u16* __restrict__ C){
  __shared__ __align__(16) u16 la[4096];
  __shared__ __align__(16) u16 lb[4096];
  gcore<0>(la, lb, A, Bt, bias, C, 3*DM, blockIdx.x*128, blockIdx.x*128, blockIdx.y*128);
}

__global__ __launch_bounds__(256) void out_gemm(const u16* __restrict__ hsb,
    const u16* __restrict__ woT, const u16* __restrict__ woaT,
    const float* __restrict__ bo, const float* __restrict__ boa, float* __restrict__ out){
  __shared__ __align__(16) u16 la[4096];
  __shared__ __align__(16) u16 lb[4096];
  int bx = blockIdx.x;
  bool txt = (bx < 4);
  int rb = bx*128;
  const u16* Bt = txt? woaT : woT;
  const float* bias = txt? boa : bo;
  float* dst = txt? out + (size_t)2048*DM : out;
  int crb = txt? rb : rb - 512;
  gcore<1>(la, lb, hsb, Bt, bias, dst, DM, rb, crb, blockIdx.y*128);
}

// ---------------- epilogue q,k: per-head RMSNorm + RoPE; Q pre-scaled by 1/sqrt(128) ----------------
__global__ __launch_bounds__(256) void epi_qk(
    const u16* __restrict__ qkvI, const u16* __restrict__ qkvT,
    const float* __restrict__ nqw, const float* __restrict__ nkw,
    const float* __restrict__ naq, const float* __restrict__ nak,
    const float* __restrict__ fcos, const float* __restrict__ fsin,
    u16* __restrict__ qh, u16* __restrict__ kh){
  int wid = blockIdx.x*4 + (threadIdx.x>>6);
  int lane = threadIdx.x&63;
  int which = wid / (NH*S_TOTC);
  int rem = wid % (NH*S_TOTC);
  int h = rem / S_TOTC, tok = rem % S_TOTC;
  const u16* src = ((tok<S_TXTC)? qkvT + (size_t)tok*(3*DM) : qkvI + (size_t)(tok-S_TXTC)*(3*DM))
                   + which*DM + h*HDM;
  const float* nw = which? ((tok<S_TXTC)? nak : nkw) : ((tok<S_TXTC)? naq : nqw);
  int d = lane*2;
  unsigned int u = *(const unsigned int*)(src + d);
  float x0 = b2f((u16)(u&0xffffu)), x1 = b2f((u16)(u>>16));
  float ss = x0*x0 + x1*x1;
  #pragma unroll
  for (int m=1;m<64;m<<=1) ss += __shfl_xor(ss, m);
  float rr = rsqrtf(ss*(1.f/128.f) + 1e-6f);
  float y0 = x0*rr*nw[d];
  float y1 = x1*rr*nw[d+1];
  float2 cc = *(const float2*)(fcos + (size_t)tok*HDM + d);
  float2 sn = *(const float2*)(fsin + (size_t)tok*HDM + d);
  float sc = which? 1.0f : 0.08838834764831845f;   // fold 1/sqrt(HD) into Q
  float o0 = (y0*cc.x - y1*sn.x)*sc;
  float o1 = (y1*cc.y + y0*sn.y)*sc;
  u16* dst = (which? kh : qh) + ((size_t)h*S_TOTC + tok)*HDM + d;
  *(unsigned int*)dst = (unsigned int)f2b(o0) | ((unsigned int)f2b(o1)<<16);
}

// ---------------- epilogue v: gather + transpose to v_t[H][HD][S_TOT] (bf16) ----------------
__global__ __launch_bounds__(256) void epi_v(const u16* __restrict__ qkvI, const u16* __restrict__ qkvT,
                                             u16* __restrict__ vt){
  __shared__ __align__(16) u16 t[64*136];
  int h = blockIdx.x % NH, tb = blockIdx.x / NH;
  int tok0 = tb*64, tid = threadIdx.x;
  #pragma unroll
  for (int i=0;i<4;i++){
    int q = tid + 256*i;
    int tr = q>>4, c8 = (q&15)*8;
    int tok = tok0 + tr;
    const u16* src = ((tok<S_TXTC)? qkvT + (size_t)tok*(3*DM) : qkvI + (size_t)(tok-S_TXTC)*(3*DM))
                     + 2*DM + h*HDM;
    *(s16x8*)&t[tr*136 + c8] = *(const s16x8*)(src + c8);
  }
  __syncthreads();
  #pragma unroll
  for (int i=0;i<4;i++){
    int q = tid + 256*i;
    int d = q>>3, j8 = (q&7)*8;
    s16x8 v;
    #pragma unroll
    for (int j=0;j<8;j++) v[j] = (short)t[(j8+j)*136 + d];
    *(s16x8*)(vt + ((size_t)h*HDM + d)*S_TOTC + tok0 + j8) = v;
  }
}

// ---------------- adapter projections: f32 (4x1024)@(1024x3072) -> bf16 [H][4][HD] ----------------
__global__ __launch_bounds__(256) void adapterk(const float* __restrict__ ad, const float* __restrict__ Wk,
        const float* __restrict__ Wv, u16* __restrict__ vdk, u16* __restrict__ vdv){
  int wid = blockIdx.x*4 + (threadIdx.x>>6);
  int lane = threadIdx.x&63;
  int tensor = wid / (4*DM);
  int rem = wid % (4*DM);
  int tok = rem / DM, col = rem % DM;
  const float* Wp = tensor? Wv : Wk;
  float s = 0.f;
  #pragma unroll
  for (int i=0;i<16;i++){
    int k = lane + 64*i;
    s += ad[tok*1024 + k] * Wp[(size_t)k*DM + col];
  }
  #pragma unroll
  for (int m=1;m<64;m<<=1) s += __shfl_xor(s, m);
  if (lane==0){
    int hh = col>>7, d = col&127;
    (tensor? vdv : vdk)[(hh*4+tok)*HDM + d] = f2b(s);
  }
}

// ---------------- fused MFMA flash attention, KVBLK=64, reg-dbuf, defer-max, 3 blocks/CU ----------------
__global__ __launch_bounds__(256) void attnk(const u16* __restrict__ qh, const u16* __restrict__ kh,
    const u16* __restrict__ vt, const u16* __restrict__ vdk, const u16* __restrict__ vdv,
    const float* __restrict__ bscale, u16* __restrict__ hs){
  __shared__ __align__(16) u16 kts[64*136];   // [key][d] stride 136
  __shared__ __align__(16) u16 vts[128*72];   // [d][key] stride 72
  __shared__ __align__(16) u16 pwb[64*72];    // [q][key] stride 72
  int h = blockIdx.y, qb = blockIdx.x*64;
  int tid = threadIdx.x, w = tid>>6, l = tid&63, g = l>>4, c16 = l&15;
  int qrow = qb + w*16 + c16;
  s16x8 qf[4];
  #pragma unroll
  for (int kc=0;kc<4;kc++) qf[kc] = *(const s16x8*)(qh + ((size_t)h*S_TOTC + qrow)*HDM + kc*32 + g*8);
  f32x4 acc[8];
  #pragma unroll
  for (int dt=0;dt<8;dt++) acc[dt] = f32x4{0.f,0.f,0.f,0.f};
  float m_[4] = {-3e38f,-3e38f,-3e38f,-3e38f};
  float l_[4] = {0.f,0.f,0.f,0.f};
  const u16* khB = kh + (size_t)h*S_TOTC*HDM;
  const u16* vtB = vt + (size_t)h*HDM*S_TOTC;

  auto LOADT = [&](s16x8* kr, s16x8* vr, int kb){
    #pragma unroll
    for (int i=0;i<4;i++){
      int idx = tid + 256*i;
      kr[i] = *(const s16x8*)(khB + (size_t)(kb + (idx>>4))*HDM + (idx&15)*8);
      vr[i] = *(const s16x8*)(vtB + (size_t)(idx>>3)*S_TOTC + kb + (idx&7)*8);
    }
  };
  auto STORET = [&](s16x8* kr, s16x8* vr){
    #pragma unroll
    for (int i=0;i<4;i++){
      int idx = tid + 256*i;
      *(s16x8*)&kts[(idx>>4)*136 + (idx&15)*8] = kr[i];
      *(s16x8*)&vts[(idx>>3)*72 + (idx&7)*8] = vr[i];
    }
  };
  auto COMPUTE = [&](){
    f32x4 s[4];
    #pragma unroll
    for (int su=0;su<4;su++) s[su] = f32x4{0.f,0.f,0.f,0.f};
    __builtin_amdgcn_s_setprio(1);
    #pragma unroll
    for (int su=0;su<4;su++)
      #pragma unroll
      for (int kc=0;kc<4;kc++){
        s16x8 kf = *(const s16x8*)&kts[(su*16+c16)*136 + (kc*4+g)*8];
        s[su] = __builtin_amdgcn_mfma_f32_16x16x32_bf16(qf[kc], kf, s[su], 0,0,0);
      }
    __builtin_amdgcn_s_setprio(0);
    float tm[4];
    #pragma unroll
    for (int r=0;r<4;r++)
      tm[r] = fmaxf(fmaxf(s[0][r],s[1][r]), fmaxf(s[2][r],s[3][r]));
    #pragma unroll
    for (int m=1;m<16;m<<=1)
      #pragma unroll
      for (int r=0;r<4;r++) tm[r] = fmaxf(tm[r], __shfl_xor(tm[r], m));
    // defer-max (T13): only rescale when max grew past THR=8
    bool need = !__all(tm[0]<=m_[0]+8.f && tm[1]<=m_[1]+8.f && tm[2]<=m_[2]+8.f && tm[3]<=m_[3]+8.f);
    if (need){
      float corr[4];
      #pragma unroll
      for (int r=0;r<4;r++){
        float mn = fmaxf(m_[r], tm[r]);
        corr[r] = __expf(m_[r]-mn);
        m_[r] = mn;
        l_[r] *= corr[r];
      }
      #pragma unroll
      for (int dt=0;dt<8;dt++)
        #pragma unroll
        for (int r=0;r<4;r++) acc[dt][r] *= corr[r];
    }
    float rs[4];
    #pragma unroll
    for (int r=0;r<4;r++){
      rs[r] = 0.f;
      #pragma unroll
      for (int su=0;su<4;su++){ s[su][r] = __expf(s[su][r]-m_[r]); rs[r] += s[su][r]; }
    }
    #pragma unroll
    for (int m=1;m<16;m<<=1)
      #pragma unroll
      for (int r=0;r<4;r++) rs[r] += __shfl_xor(rs[r], m);
    #pragma unroll
    for (int r=0;r<4;r++) l_[r] += rs[r];
    #pragma unroll
    for (int su=0;su<4;su++)
      #pragma unroll
      for (int r=0;r<4;r++)
        pwb[(w*16 + g*4 + r)*72 + su*16 + c16] = f2b(s[su][r]);
    s16x8 pf0 = *(const s16x8*)&pwb[(w*16 + c16)*72 + g*8];
    s16x8 pf1 = *(const s16x8*)&pwb[(w*16 + c16)*72 + 32 + g*8];
    __builtin_amdgcn_s_setprio(1);
    #pragma unroll
    for (int dt=0;dt<8;dt++){
      s16x8 vf0 = *(const s16x8*)&vts[(dt*16 + c16)*72 + g*8];
      acc[dt] = __builtin_amdgcn_mfma_f32_16x16x32_bf16(pf0, vf0, acc[dt], 0,0,0);
      s16x8 vf1 = *(const s16x8*)&vts[(dt*16 + c16)*72 + 32 + g*8];
      acc[dt] = __builtin_amdgcn_mfma_f32_16x16x32_bf16(pf1, vf1, acc[dt], 0,0,0);
    }
    __builtin_amdgcn_s_setprio(0);
  };

  s16x8 ka[4], va[4], kb2[4], vb2[4];
  LOADT(ka, va, 0);
  for (int kb=0; kb<S_TOTC; kb+=128){
    STORET(ka, va);
    __syncthreads();
    LOADT(kb2, vb2, kb+64);
    COMPUTE();
    __syncthreads();
    STORET(kb2, vb2);
    __syncthreads();
    if (kb+128 < S_TOTC) LOADT(ka, va, kb+128);
    COMPUTE();
    __syncthreads();
  }

  // adapter cross-attention: stage 4 K rows / 4 V keys into kts/vts (stale rest is masked)
  if (tid < 64){
    int key = tid>>4, c8 = (tid&15)*8;
    *(s16x8*)&kts[key*136 + c8] = *(const s16x8*)(vdk + (h*4+key)*HDM + c8);
  } else if (tid < 192){
    int d = tid - 64;
    #pragma unroll
    for (int key=0;key<4;key++) vts[d*72 + key] = vdv[(h*4+key)*HDM + d];
  }
  __syncthreads();
  f32x4 s2 = {0.f,0.f,0.f,0.f};
  #pragma unroll
  for (int kc=0;kc<4;kc++){
    s16x8 kf = *(const s16x8*)&kts[c16*136 + (kc*4+g)*8];
    s2 = __builtin_amdgcn_mfma_f32_16x16x32_bf16(qf[kc], kf, s2, 0,0,0);
  }
  bool valid = (c16 < 4);
  float m2[4], l2[4];
  #pragma unroll
  for (int r=0;r<4;r++) m2[r] = valid? s2[r] : -3e38f;
  #pragma unroll
  for (int m=1;m<16;m<<=1)
    #pragma unroll
    for (int r=0;r<4;r++) m2[r] = fmaxf(m2[r], __shfl_xor(m2[r], m));
  #pragma unroll
  for (int r=0;r<4;r++){ float p = valid? __expf(s2[r]-m2[r]) : 0.f; s2[r]=p; l2[r]=p; }
  #pragma unroll
  for (int m=1;m<16;m<<=1)
    #pragma unroll
    for (int r=0;r<4;r++) l2[r] += __shfl_xor(l2[r], m);
  #pragma unroll
  for (int r=0;r<4;r++){
    pwb[(w*16 + g*4 + r)*72 + c16]      = f2b(s2[r]);
    pwb[(w*16 + g*4 + r)*72 + 16 + c16] = (u16)0;
  }
  s16x8 pf2 = *(const s16x8*)&pwb[(w*16 + c16)*72 + g*8];
  f32x4 a2[8];
  #pragma unroll
  for (int dt=0;dt<8;dt++) a2[dt] = f32x4{0.f,0.f,0.f,0.f};
  #pragma unroll
  for (int dt=0;dt<8;dt++){
    s16x8 vf = *(const s16x8*)&vts[(dt*16 + c16)*72 + g*8];
    a2[dt] = __builtin_amdgcn_mfma_f32_16x16x32_bf16(pf2, vf, a2[dt], 0,0,0);
  }
  float sb = bscale[0];
  float rl[4], rl2[4];
  #pragma unroll
  for (int r=0;r<4;r++){ rl[r] = 1.f/l_[r]; rl2[r] = sb/l2[r]; }
  #pragma unroll
  for (int dt=0;dt<8;dt++)
    #pragma unroll
    for (int r=0;r<4;r++){
      int tok = qb + w*16 + g*4 + r;
      int col = h*HDM + dt*16 + c16;
      hs[(size_t)tok*DM + col] = f2b(acc[dt][r]*rl[r] + a2[dt][r]*rl2[r]);
    }
}

extern "C" void kernel_launch(void* const* d_in, const int* in_sizes, int n_in,
                              void* d_out, int out_size, void* d_ws, size_t ws_size,
                              hipStream_t stream){
  static const int expect[28] = {
    6291456, 1572864, 4096, 327680, 327680,
    9437184, 3072, 9437184, 3072, 9437184, 3072, 128, 128,
    9437184, 3072, 9437184, 3072, 9437184, 3072, 128, 128,
    9437184, 3072, 9437184, 3072, 3145728, 3145728, 1 };
  bool ok = (n_in == 28);
  if (ok) for (int i=0;i<28;i++) if (in_sizes[i] != expect[i]) { ok = false; break; }
  if (!ok){ fillv<<<(out_size+255)/256,256,0,stream>>>((float*)d_out, out_size, 7.0f); return; }
  if (ws_size < 119611392ull){ fillv<<<(out_size+255)/256,256,0,stream>>>((float*)d_out, out_size, 9.0f); return; }

  const float* hidden = (const float*)d_in[0];
  const float* enc    = (const float*)d_in[1];
  const float* adapt  = (const float*)d_in[2];
  const float* fcos   = (const float*)d_in[3];
  const float* fsin   = (const float*)d_in[4];
  const float* Wq  = (const float*)d_in[5];  const float* bq  = (const float*)d_in[6];
  const float* Wk  = (const float*)d_in[7];  const float* bk  = (const float*)d_in[8];
  const float* Wv  = (const float*)d_in[9];  const float* bv  = (const float*)d_in[10];
  const float* nqw = (const float*)d_in[11]; const float* nkw = (const float*)d_in[12];
  const float* Wqa = (const float*)d_in[13]; const float* bqa = (const float*)d_in[14];
  const float* Wka = (const float*)d_in[15]; const float* bka = (const float*)d_in[16];
  const float* Wva = (const float*)d_in[17]; const float* bva = (const float*)d_in[18];
  const float* naq = (const float*)d_in[19]; const float* nak = (const float*)d_in[20];
  const float* Wo  = (const float*)d_in[21]; const float* bo  = (const float*)d_in[22];
  const float* Woa = (const float*)d_in[23]; const float* boa = (const float*)d_in[24];
  const float* Wkad = (const float*)d_in[25]; const float* Wvad = (const float*)d_in[26];
  const float* bsc  = (const float*)d_in[27];
  float* out = (float*)d_out;

  // ws layout (bytes), peak ~119.6 MB with lifetime overlap
  char* ws = (char*)d_ws;
  u16* wt3   = (u16*)(ws);                  // [0, 56,623,104): 3 transposed weights
  u16* kh    = (u16*)(ws);                  //   after qkv gemms: kh (15,728,640)
  u16* vth   = (u16*)(ws + 15728640);       //   vth (15,728,640)
  u16* vdk   = (u16*)(ws + 31457280);       //   vdk/vdv (24,576 each)
  u16* vdv   = (u16*)(ws + 31481856);
  u16* woaT  = (u16*)(ws + 33554432);       //   Woa^T (18,874,368)
  u16* hbf   = (u16*)(ws + 56623104);       // hidden bf16 (12,582,912)
  u16* ebf   = (u16*)(ws + 69206016);       // enc bf16 (3,145,728), contiguous after hbf
  u16* qh    = (u16*)(ws + 56623104);       //   after txt gemm: qh (15,728,640)
  u16* qkvI  = (u16*)(ws + 72351744);       // img QKV [2048][9216]
  u16* hsb   = (u16*)(ws + 72351744);       //   after epi: hsb bf16 [2560][3072]
  u16* woT   = (u16*)(ws + 88080384);       //   Wo^T (18,874,368)
  u16* qkvT  = (u16*)(ws + 110100480);      // txt QKV [512][9216]
  float* biasA = (float*)(ws + 119537664);  // 2x9216 fp32, contiguous
  float* biasB = (float*)(ws + 119574528);

  dim3 tg(48,48);
  cast2<<<3840,256,0,stream>>>(hidden, enc, hbf, 786432, 983040);
  catbias2<<<72,256,0,stream>>>(bq,bk,bv, bqa,bka,bva, biasA);
  // img QKV
  ktrans3<<<dim3(48,48,3),256,0,stream>>>(Wq, Wk, Wv, wt3, wt3 + (size_t)DM*DM, wt3 + (size_t)2*DM*DM);
  qkv_gemm<<<dim3(16,72),256,0,stream>>>(hbf, wt3, biasA, qkvI);
  // txt QKV (reuse wt3)
  ktrans3<<<dim3(48,48,3),256,0,stream>>>(Wqa, Wka, Wva, wt3, wt3 + (size_t)DM*DM, wt3 + (size_t)2*DM*DM);
  qkv_gemm<<<dim3(4,72),256,0,stream>>>(ebf, wt3, biasB, qkvT);
  // epilogues + adapter
  epi_qk<<<30720,256,0,stream>>>(qkvI, qkvT, nqw,nkw,naq,nak, fcos,fsin, qh, kh);
  epi_v<<<24*40,256,0,stream>>>(qkvI, qkvT, vth);
  adapterk<<<6144,256,0,stream>>>(adapt, Wkad, Wvad, vdk, vdv);
  // attention -> bf16 hsb
  attnk<<<dim3(40,24),256,0,stream>>>(qh, kh, vth, vdk, vdv, bsc, hsb);
  // output projections
  ktrans3<<<dim3(48,48,2),256,0,stream>>>(Wo, Woa, Woa, woT, woaT, woaT);
  out_gemm<<<dim3(20,24),256,0,stream>>>(hsb, woT, woaT, bo, boa, out);
}